// Round 7
// baseline (2842.773 us; speedup 1.0000x reference)
//
#include <hip/hip_runtime.h>

#define AS1 __attribute__((address_space(1)))
#define AS3 __attribute__((address_space(3)))

typedef __attribute__((ext_vector_type(4))) float f32x4;
typedef __attribute__((ext_vector_type(8))) short s16x8;

__device__ __forceinline__ void gl_lds16(void* lds, const void* g) {
    // async global->LDS, 16B/lane: LDS dest = wave-uniform base + lane*16
    __builtin_amdgcn_global_load_lds((const AS1 unsigned int*)g,
                                     (AS3 unsigned int*)lds, 16, 0, 0);
}

__device__ __forceinline__ unsigned short f2bf(float f) {
    unsigned int u = __float_as_uint(f);
    u = (u + 0x7FFFu + ((u >> 16) & 1u)) >> 16;   // RNE
    return (unsigned short)u;
}

// ---------------------------------------------------------------------------
// K1: X0[r=t*8+b][1024] = emb[x[b,t]] @ W_ih0 + b_ih0 + b_hh0
// ---------------------------------------------------------------------------
__global__ __launch_bounds__(256) void k_x0(const int* __restrict__ x,
                                            const float* __restrict__ emb,
                                            const float* __restrict__ Wih0,
                                            const float* __restrict__ bih0,
                                            const float* __restrict__ bhh0,
                                            float* __restrict__ X0) {
    __shared__ float elds[16][256];
    const int tid = threadIdx.x, blk = blockIdx.x;
    const int r0 = blk * 16;
    {   // stage 16 embedding rows
        const int rr = tid >> 4, sg = tid & 15;
        const int r = r0 + rr, tt = r >> 3, bb = r & 7;
        const int tok = x[bb * 512 + tt];
        const float4* ep = (const float4*)(emb + (size_t)tok * 256);
        float4* el = (float4*)(&elds[rr][0]);
#pragma unroll
        for (int j = 0; j < 4; ++j) el[sg * 4 + j] = ep[sg * 4 + j];
    }
    __syncthreads();
    float acc[16][4];
#pragma unroll
    for (int a = 0; a < 16; ++a) { acc[a][0]=0.f; acc[a][1]=0.f; acc[a][2]=0.f; acc[a][3]=0.f; }
    const int c0 = tid * 4;
    for (int k = 0; k < 256; ++k) {
        const float4 w = *(const float4*)(Wih0 + (size_t)k * 1024 + c0);
#pragma unroll
        for (int a = 0; a < 16; ++a) {
            const float e = elds[a][k];
            acc[a][0] += e * w.x; acc[a][1] += e * w.y;
            acc[a][2] += e * w.z; acc[a][3] += e * w.w;
        }
    }
    const float4 bi = *(const float4*)(bih0 + c0);
    const float4 bh = *(const float4*)(bhh0 + c0);
#pragma unroll
    for (int a = 0; a < 16; ++a) {
        float4 o;
        o.x = acc[a][0] + bi.x + bh.x; o.y = acc[a][1] + bi.y + bh.y;
        o.z = acc[a][2] + bi.z + bh.z; o.w = acc[a][3] + bi.w + bh.w;
        *(float4*)(X0 + (size_t)(r0 + a) * 1024 + c0) = o;
    }
}

// ---------------------------------------------------------------------------
// K2: persistent scan + hidden W_out transpose.
// blocks 0..63: layer0 (16 cols each); 64..191: layer1 (8 cols each);
// blocks 192..255: WT[n][k] = bf16(W_out[k][n]) on the 64 otherwise-idle CUs
// (scan is latency-bound at 1 block/CU; wt blocks never touch flags, so the
// sync topology is unchanged; grid 256 = CU count, all blocks resident).
// Sync design: ROUND-1 VALIDATED CONFIGURATION (do not modify):
//  - H0/H1 row stores are __hip_atomic_store(RELAXED, AGENT) => sc0 sc1
//    write-through to the coherence point. __syncthreads drains vmcnt, then
//    tid0 publishes via atomic_fetch_add on ONE PACKED counter per (layer,t).
//    (R5: line-strided counters FAILED correctness — packed is validated.)
//  - Consumers: ONLY wave 0 polls, same-address load, s_sleep(1) paced.
//    (R2/R3/R4: wider footprint / more pollers / unpaced all regressed.)
//  - Layer1 stages h0_t and h1_{t-1} in ONE phase into two LDS buffers.
//  - X0 contribution prefetched before the poll.
// Layout H0/H1: [t+1][k][b] (b fastest); row 0 = zeros (initial state).
// ---------------------------------------------------------------------------
__global__ __launch_bounds__(256) void k_scan(
    const float* __restrict__ X0, float* __restrict__ H0, float* __restrict__ H1,
    unsigned short* __restrict__ H1b,
    const float* __restrict__ Whh0, const float* __restrict__ Wih1,
    const float* __restrict__ Whh1,
    const float* __restrict__ bih1, const float* __restrict__ bhh1,
    int* __restrict__ cnt0, int* __restrict__ cnt1,
    float* __restrict__ oh0, float* __restrict__ oh1,
    const float* __restrict__ Wout, unsigned short* __restrict__ WT) {
    __shared__ float smem[20736];          // 82944 B (gfx950 LDS = 160 KiB)
    float* hl0  = smem;                    // 8192 floats: staged h (layer-input)
    float* hl1  = smem + 8192;             // 8192 floats: staged h (recurrent, layer1)
    float* part = smem + 16384;            // partial sums (<= 4352 floats)
    const int tid = threadIdx.x, bid = blockIdx.x;
    const int wv = tid >> 6, lid = tid & 63;

    if (bid < 64) {
        // ================= layer 0 =================
        const int j = bid, c0 = j * 16;
        const int ks = tid >> 3, cp = tid & 7;   // ks 0..31 (32 k's each), 8 col-pairs
        float2 w[32];
#pragma unroll
        for (int i = 0; i < 32; ++i)
            w[i] = *(const float2*)(Whh0 + (size_t)(i * 32 + ks) * 1024 + c0 + cp * 2);
        const int rb = tid & 7, rc = tid >> 3;   // reducers (tid<128): rc 0..15

        for (int t = 0; t < 512; ++t) {
            // prefetch X0 contribution (off the post-reduce critical path)
            float xv = 0.f;
            if (tid < 128) xv = X0[(size_t)(t * 8 + rb) * 1024 + c0 + rc];
            if (t > 0 && wv == 0) {
                int v = __hip_atomic_load(&cnt0[t - 1], __ATOMIC_RELAXED, __HIP_MEMORY_SCOPE_AGENT);
                while (v < 64) {
                    __builtin_amdgcn_s_sleep(1);
                    v = __hip_atomic_load(&cnt0[t - 1], __ATOMIC_RELAXED, __HIP_MEMORY_SCOPE_AGENT);
                }
            }
            asm volatile("" ::: "memory");
            __syncthreads();
            {   // stage h0_{t-1} (row t): normal cached global->LDS
                const float* src = H0 + (size_t)t * 8192;
#pragma unroll
                for (int q = 0; q < 8; ++q) {
                    const int ch = wv * 8 + q;
                    gl_lds16(hl0 + ch * 256, src + ch * 256 + lid * 4);
                }
            }
            __syncthreads();
            float y0[8], y1[8];
#pragma unroll
            for (int b = 0; b < 8; ++b) { y0[b] = 0.f; y1[b] = 0.f; }
#pragma unroll
            for (int i = 0; i < 32; ++i) {
                const int k = i * 32 + ks;
                const float4 ha = *(const float4*)(hl0 + (k << 3));
                const float4 hb = *(const float4*)(hl0 + (k << 3) + 4);
                const float wa = w[i].x, wb = w[i].y;
                y0[0] += ha.x * wa; y0[1] += ha.y * wa; y0[2] += ha.z * wa; y0[3] += ha.w * wa;
                y0[4] += hb.x * wa; y0[5] += hb.y * wa; y0[6] += hb.z * wa; y0[7] += hb.w * wa;
                y1[0] += ha.x * wb; y1[1] += ha.y * wb; y1[2] += ha.z * wb; y1[3] += ha.w * wb;
                y1[4] += hb.x * wb; y1[5] += hb.y * wb; y1[6] += hb.z * wb; y1[7] += hb.w * wb;
            }
#pragma unroll
            for (int b = 0; b < 8; ++b) {
                part[ks * 136 + (cp * 2 + 0) * 8 + b] = y0[b];
                part[ks * 136 + (cp * 2 + 1) * 8 + b] = y1[b];
            }
            __syncthreads();
            if (tid < 128) {
                float s = 0.f;
                for (int kr = 0; kr < 32; ++kr) s += part[kr * 136 + rc * 8 + rb];
                s += xv;
                const float hv = tanhf(s);
                // coherent write-through store (sc0 sc1): no wbl2 needed later
                __hip_atomic_store(&H0[(size_t)(t + 1) * 8192 + (c0 + rc) * 8 + rb], hv,
                                   __ATOMIC_RELAXED, __HIP_MEMORY_SCOPE_AGENT);
                if (t == 511) oh0[rb * 1024 + c0 + rc] = hv;
            }
            __syncthreads();   // drains vmcnt(0): stores are at coherence point
            if (tid == 0)
                __hip_atomic_fetch_add(&cnt0[t], 1, __ATOMIC_RELAXED, __HIP_MEMORY_SCOPE_AGENT);
        }
    } else if (bid < 192) {
        // ================= layer 1 =================
        const int j = bid - 64, c0 = j * 8;
        const int ks = tid >> 2, cp = tid & 3;   // ks 0..63 (16 k's each), 4 col-pairs
        float2 wi[16], wh[16];
#pragma unroll
        for (int i = 0; i < 16; ++i) {
            wi[i] = *(const float2*)(Wih1 + (size_t)(i * 64 + ks) * 1024 + c0 + cp * 2);
            wh[i] = *(const float2*)(Whh1 + (size_t)(i * 64 + ks) * 1024 + c0 + cp * 2);
        }
        const int rb = tid & 7, rc = tid >> 3;   // reducers (tid<64): rc 0..7
        float biasc = 0.f;
        if (tid < 64) biasc = bih1[c0 + rc] + bhh1[c0 + rc];

        for (int t = 0; t < 512; ++t) {
            if (wv == 0) {
                int v = __hip_atomic_load(&cnt0[t], __ATOMIC_RELAXED, __HIP_MEMORY_SCOPE_AGENT);
                while (v < 64) {
                    __builtin_amdgcn_s_sleep(1);
                    v = __hip_atomic_load(&cnt0[t], __ATOMIC_RELAXED, __HIP_MEMORY_SCOPE_AGENT);
                }
            } else if (t > 0 && wv == 1) {
                int v = __hip_atomic_load(&cnt1[t - 1], __ATOMIC_RELAXED, __HIP_MEMORY_SCOPE_AGENT);
                while (v < 128) {
                    __builtin_amdgcn_s_sleep(1);
                    v = __hip_atomic_load(&cnt1[t - 1], __ATOMIC_RELAXED, __HIP_MEMORY_SCOPE_AGENT);
                }
            }
            asm volatile("" ::: "memory");
            __syncthreads();
            {   // stage h0_t (row t+1) AND h1_{t-1} (row t) in one phase
                const float* s0 = H0 + (size_t)(t + 1) * 8192;
                const float* s1 = H1 + (size_t)t * 8192;
#pragma unroll
                for (int q = 0; q < 8; ++q) {
                    const int ch = wv * 8 + q;
                    gl_lds16(hl0 + ch * 256, s0 + ch * 256 + lid * 4);
                    gl_lds16(hl1 + ch * 256, s1 + ch * 256 + lid * 4);
                }
            }
            __syncthreads();
            float y0[8], y1[8];
#pragma unroll
            for (int b = 0; b < 8; ++b) { y0[b] = 0.f; y1[b] = 0.f; }
#pragma unroll
            for (int i = 0; i < 16; ++i) {
                const int k = i * 64 + ks;
                const float4 ha = *(const float4*)(hl0 + (k << 3));
                const float4 hb = *(const float4*)(hl0 + (k << 3) + 4);
                const float4 ga = *(const float4*)(hl1 + (k << 3));
                const float4 gb = *(const float4*)(hl1 + (k << 3) + 4);
                {   const float wa = wi[i].x, wb = wi[i].y;
                    y0[0] += ha.x * wa; y0[1] += ha.y * wa; y0[2] += ha.z * wa; y0[3] += ha.w * wa;
                    y0[4] += hb.x * wa; y0[5] += hb.y * wa; y0[6] += hb.z * wa; y0[7] += hb.w * wa;
                    y1[0] += ha.x * wb; y1[1] += ha.y * wb; y1[2] += ha.z * wb; y1[3] += ha.w * wb;
                    y1[4] += hb.x * wb; y1[5] += hb.y * wb; y1[6] += hb.z * wb; y1[7] += hb.w * wb; }
                {   const float wa = wh[i].x, wb = wh[i].y;
                    y0[0] += ga.x * wa; y0[1] += ga.y * wa; y0[2] += ga.z * wa; y0[3] += ga.w * wa;
                    y0[4] += gb.x * wa; y0[5] += gb.y * wa; y0[6] += gb.z * wa; y0[7] += gb.w * wa;
                    y1[0] += ga.x * wb; y1[1] += ga.y * wb; y1[2] += ga.z * wb; y1[3] += ga.w * wb;
                    y1[4] += gb.x * wb; y1[5] += gb.y * wb; y1[6] += gb.z * wb; y1[7] += gb.w * wb; }
            }
#pragma unroll
            for (int b = 0; b < 8; ++b) {
                part[ks * 65 + (cp * 2 + 0) * 8 + b] = y0[b];
                part[ks * 65 + (cp * 2 + 1) * 8 + b] = y1[b];
            }
            __syncthreads();
            if (tid < 64) {
                float s = biasc;
                for (int kr = 0; kr < 64; ++kr) s += part[kr * 65 + rc * 8 + rb];
                const float hv = tanhf(s);
                __hip_atomic_store(&H1[(size_t)(t + 1) * 8192 + (c0 + rc) * 8 + rb], hv,
                                   __ATOMIC_RELAXED, __HIP_MEMORY_SCOPE_AGENT);
                H1b[(size_t)(rb * 512 + t) * 1024 + c0 + rc] = f2bf(hv);  // cached; read next kernel
                if (t == 511) oh1[rb * 1024 + c0 + rc] = hv;
            }
            __syncthreads();   // drains vmcnt(0): stores are at coherence point
            if (tid == 0)
                __hip_atomic_fetch_add(&cnt1[t], 1, __ATOMIC_RELAXED, __HIP_MEMORY_SCOPE_AGENT);
        }
    } else {
        // ============ blocks 192..255: W_out transpose (hidden) ============
        unsigned short* lt = (unsigned short*)smem;   // 128*136*2 = 34816 B <= 82944
        for (int tile = bid - 192; tile < 2000; tile += 64) {
            const int kt = tile / 250, ntw = tile % 250;
            const int krow = tid >> 5, ncol = (tid & 31) * 4;
            for (int it = 0; it < 16; ++it) {
                const int kl = it * 8 + krow;
                const float4 v = *(const float4*)(Wout + (size_t)(kt * 128 + kl) * 32000 + ntw * 128 + ncol);
                lt[(ncol + 0) * 136 + kl] = f2bf(v.x);
                lt[(ncol + 1) * 136 + kl] = f2bf(v.y);
                lt[(ncol + 2) * 136 + kl] = f2bf(v.z);
                lt[(ncol + 3) * 136 + kl] = f2bf(v.w);
            }
            __syncthreads();
            const int sg = tid & 15;
            for (int ot = 0; ot < 8; ++ot) {
                const int nl = ot * 16 + (tid >> 4);
                const uint4 u = *(uint4*)&lt[nl * 136 + sg * 8];
                *(uint4*)(WT + (size_t)(ntw * 128 + nl) * 1024 + kt * 128 + sg * 8) = u;
            }
            __syncthreads();   // lt reused next tile
        }
    }
}

// ---------------------------------------------------------------------------
// K3: logits[m=b*512+t][n] = H1b[m][:] @ W_out[:, n] + b_out[n]
// m97-style: 128x128 tile, BK=64, 4 waves 2x2, 16x16x32 bf16 MFMA.
// A = H1b [4096][1024] bf16, B = WT [32000][1024] bf16 (= W_out^T).
// Round-7: mt-fastest block decode (resident window = 8 B-panels x 32
// m-tiles -> B panel reused 4x per XCD-L2 instead of 250 distinct panels),
// and LDS-staged epilogue: float4 512B-contiguous C stores (was scalar 4B).
// ---------------------------------------------------------------------------
__global__ __launch_bounds__(256) void k_logits(const unsigned short* __restrict__ A,
                                                const unsigned short* __restrict__ Bt,
                                                const float* __restrict__ bout,
                                                float* __restrict__ C) {
    __shared__ __align__(16) char sbuf[64 * 132 * 4];   // 33792 B
    unsigned short* Al = (unsigned short*)sbuf;         // 128*64 bf16 = 16 KB
    unsigned short* Bl = Al + 128 * 64;                 // 128*64 bf16 = 16 KB
    float* Cst = (float*)sbuf;                          // [64][132] f32 (epilogue)
    const int tid = threadIdx.x;
    const int mt = blockIdx.x & 31, nt = blockIdx.x >> 5;   // mt-fastest
    const size_t m0 = (size_t)mt * 128, n0 = (size_t)nt * 128;
    const int wv = tid >> 6, lane = tid & 63;
    const int wm = wv & 1, wn = wv >> 1;
    const int row8 = lane >> 3, sg = lane & 7;
    const int lr = lane & 15, qd = lane >> 4;

    f32x4 acc[4][4];
#pragma unroll
    for (int mi = 0; mi < 4; ++mi)
#pragma unroll
        for (int ni = 0; ni < 4; ++ni) acc[mi][ni] = (f32x4)(0.f);

    for (int kb = 0; kb < 16; ++kb) {
#pragma unroll
        for (int q = 0; q < 4; ++q) {
            const int rbase = wv * 32 + q * 8;
            gl_lds16(Al + rbase * 64, A + (m0 + rbase + row8) * 1024 + kb * 64 + sg * 8);
            gl_lds16(Bl + rbase * 64, Bt + (n0 + rbase + row8) * 1024 + kb * 64 + sg * 8);
        }
        __syncthreads();
#pragma unroll
        for (int kk = 0; kk < 2; ++kk) {
            s16x8 af[4], bfr[4];
#pragma unroll
            for (int mi = 0; mi < 4; ++mi)
                af[mi] = *(const s16x8*)&Al[(wm * 64 + mi * 16 + lr) * 64 + kk * 32 + qd * 8];
#pragma unroll
            for (int ni = 0; ni < 4; ++ni)
                bfr[ni] = *(const s16x8*)&Bl[(wn * 64 + ni * 16 + lr) * 64 + kk * 32 + qd * 8];
#pragma unroll
            for (int mi = 0; mi < 4; ++mi)
#pragma unroll
                for (int ni = 0; ni < 4; ++ni)
                    acc[mi][ni] = __builtin_amdgcn_mfma_f32_16x16x32_bf16(af[mi], bfr[ni], acc[mi][ni], 0, 0, 0);
        }
        __syncthreads();
    }
    // Epilogue: stage each 64-row half in LDS, write coalesced float4 rows.
    const int rw0 = tid >> 5;            // 0..7
    const int c4 = (tid & 31) * 4;       // 0..124
    const float4 bo4 = *(const float4*)(bout + n0 + c4);
#pragma unroll
    for (int h = 0; h < 2; ++h) {
        if (wm == h) {
#pragma unroll
            for (int mi = 0; mi < 4; ++mi)
#pragma unroll
                for (int ni = 0; ni < 4; ++ni)
#pragma unroll
                    for (int r = 0; r < 4; ++r)
                        Cst[(mi * 16 + qd * 4 + r) * 132 + wn * 64 + ni * 16 + lr] = acc[mi][ni][r];
        }
        __syncthreads();
        for (int rr = rw0; rr < 64; rr += 8) {
            float4 v = *(float4*)&Cst[rr * 132 + c4];
            v.x += bo4.x; v.y += bo4.y; v.z += bo4.z; v.w += bo4.w;
            *(float4*)(C + (size_t)(m0 + h * 64 + rr) * 32000 + n0 + c4) = v;
        }
        __syncthreads();
    }
}

// ---------------------------------------------------------------------------
extern "C" void kernel_launch(void* const* d_in, const int* in_sizes, int n_in,
                              void* d_out, int out_size, void* d_ws, size_t ws_size,
                              hipStream_t stream) {
    const int* x      = (const int*)d_in[0];
    const float* emb  = (const float*)d_in[1];
    const float* Wih0 = (const float*)d_in[2];
    const float* bih0 = (const float*)d_in[3];
    const float* Whh0 = (const float*)d_in[4];
    const float* bhh0 = (const float*)d_in[5];
    const float* Wih1 = (const float*)d_in[6];
    const float* bih1 = (const float*)d_in[7];
    const float* Whh1 = (const float*)d_in[8];
    const float* bhh1 = (const float*)d_in[9];
    const float* Wout = (const float*)d_in[10];
    const float* bout = (const float*)d_in[11];

    char* ws = (char*)d_ws;
    float* X0           = (float*)(ws + 0);          // 16,777,216 B
    float* H0           = (float*)(ws + 16777216);   // 513*8192*4 = 16,809,984 B
    float* H1           = (float*)(ws + 33587200);   // 16,809,984 B
    unsigned short* H1b = (unsigned short*)(ws + 50397184);  // 8,388,608 B
    unsigned short* WT  = (unsigned short*)(ws + 58785792);  // 65,536,000 B
    int* cnt0           = (int*)(ws + 124321792);    // 512*4 = 2048 B
    int* cnt1           = cnt0 + 512;                // 512*4 = 2048 B

    float* out = (float*)d_out;
    float* oh0 = out + 131072000ll;   // 4096*32000
    float* oh1 = oh0 + 8192;

    // ws is re-poisoned before every launch: re-zero initial states + counters
    hipMemsetAsync(H0, 0, 32768, stream);
    hipMemsetAsync(H1, 0, 32768, stream);
    hipMemsetAsync(cnt0, 0, 4096, stream);

    k_x0<<<256, 256, 0, stream>>>(x, emb, Wih0, bih0, bhh0, X0);
    k_scan<<<256, 256, 0, stream>>>(X0, H0, H1, H1b, Whh0, Wih1, Whh1,
                                    bih1, bhh1, cnt0, cnt1, oh0, oh1, Wout, WT);
    k_logits<<<8000, 256, 0, stream>>>(H1b, WT, bout, out);
}

// Round 9
// 2706.975 us; speedup vs baseline: 1.0502x; 1.0502x over previous
//
#include <hip/hip_runtime.h>

#define AS1 __attribute__((address_space(1)))
#define AS3 __attribute__((address_space(3)))

typedef __attribute__((ext_vector_type(4))) float f32x4;
typedef __attribute__((ext_vector_type(8))) short s16x8;

__device__ __forceinline__ void gl_lds16(void* lds, const void* g) {
    // async global->LDS, 16B/lane: LDS dest = wave-uniform base + lane*16
    __builtin_amdgcn_global_load_lds((const AS1 unsigned int*)g,
                                     (AS3 unsigned int*)lds, 16, 0, 0);
}

__device__ __forceinline__ unsigned short f2bf(float f) {
    unsigned int u = __float_as_uint(f);
    u = (u + 0x7FFFu + ((u >> 16) & 1u)) >> 16;   // RNE
    return (unsigned short)u;
}

// ---------------------------------------------------------------------------
// K1: X0[r=t*8+b][1024] = emb[x[b,t]] @ W_ih0 + b_ih0 + b_hh0
// ---------------------------------------------------------------------------
__global__ __launch_bounds__(256) void k_x0(const int* __restrict__ x,
                                            const float* __restrict__ emb,
                                            const float* __restrict__ Wih0,
                                            const float* __restrict__ bih0,
                                            const float* __restrict__ bhh0,
                                            float* __restrict__ X0) {
    __shared__ float elds[16][256];
    const int tid = threadIdx.x, blk = blockIdx.x;
    const int r0 = blk * 16;
    {   // stage 16 embedding rows
        const int rr = tid >> 4, sg = tid & 15;
        const int r = r0 + rr, tt = r >> 3, bb = r & 7;
        const int tok = x[bb * 512 + tt];
        const float4* ep = (const float4*)(emb + (size_t)tok * 256);
        float4* el = (float4*)(&elds[rr][0]);
#pragma unroll
        for (int j = 0; j < 4; ++j) el[sg * 4 + j] = ep[sg * 4 + j];
    }
    __syncthreads();
    float acc[16][4];
#pragma unroll
    for (int a = 0; a < 16; ++a) { acc[a][0]=0.f; acc[a][1]=0.f; acc[a][2]=0.f; acc[a][3]=0.f; }
    const int c0 = tid * 4;
    for (int k = 0; k < 256; ++k) {
        const float4 w = *(const float4*)(Wih0 + (size_t)k * 1024 + c0);
#pragma unroll
        for (int a = 0; a < 16; ++a) {
            const float e = elds[a][k];
            acc[a][0] += e * w.x; acc[a][1] += e * w.y;
            acc[a][2] += e * w.z; acc[a][3] += e * w.w;
        }
    }
    const float4 bi = *(const float4*)(bih0 + c0);
    const float4 bh = *(const float4*)(bhh0 + c0);
#pragma unroll
    for (int a = 0; a < 16; ++a) {
        float4 o;
        o.x = acc[a][0] + bi.x + bh.x; o.y = acc[a][1] + bi.y + bh.y;
        o.z = acc[a][2] + bi.z + bh.z; o.w = acc[a][3] + bi.w + bh.w;
        *(float4*)(X0 + (size_t)(r0 + a) * 1024 + c0) = o;
    }
}

// ---------------------------------------------------------------------------
// K2: persistent scan + hidden W_out transpose (ROUND-7 VALIDATED, verbatim).
// blocks 0..63: layer0; 64..191: layer1; 192..255: WT transpose on idle CUs.
// Scan sync: ROUND-1 VALIDATED CONFIGURATION (do not modify):
//  - H0/H1 row stores sc0sc1 write-through; __syncthreads drains vmcnt;
//    tid0 publishes via atomic_fetch_add on ONE PACKED counter per (layer,t).
//    (R5: line-strided counters FAILED. R8: adding same-dispatch consumers
//    of H1b/WT FAILED. The fence-free model is validated ONLY for this
//    exact consumer topology — overlap work across dispatches instead.)
//  - Consumers: ONLY wave 0 polls, same-address load, s_sleep(1) paced.
//  - Layer1 stages h0_t and h1_{t-1} in ONE phase into two LDS buffers.
//  - X0 contribution prefetched before the poll.
// Layout H0/H1: [t+1][k][b] (b fastest); row 0 = zeros (initial state).
// ---------------------------------------------------------------------------
__global__ __launch_bounds__(256) void k_scan(
    const float* __restrict__ X0, float* __restrict__ H0, float* __restrict__ H1,
    unsigned short* __restrict__ H1b,
    const float* __restrict__ Whh0, const float* __restrict__ Wih1,
    const float* __restrict__ Whh1,
    const float* __restrict__ bih1, const float* __restrict__ bhh1,
    int* __restrict__ cnt0, int* __restrict__ cnt1,
    float* __restrict__ oh0, float* __restrict__ oh1,
    const float* __restrict__ Wout, unsigned short* __restrict__ WT) {
    __shared__ float smem[20736];          // 82944 B (gfx950 LDS = 160 KiB)
    float* hl0  = smem;                    // 8192 floats: staged h (layer-input)
    float* hl1  = smem + 8192;             // 8192 floats: staged h (recurrent, layer1)
    float* part = smem + 16384;            // partial sums (<= 4352 floats)
    const int tid = threadIdx.x, bid = blockIdx.x;
    const int wv = tid >> 6, lid = tid & 63;

    if (bid < 64) {
        // ================= layer 0 =================
        const int j = bid, c0 = j * 16;
        const int ks = tid >> 3, cp = tid & 7;   // ks 0..31 (32 k's each), 8 col-pairs
        float2 w[32];
#pragma unroll
        for (int i = 0; i < 32; ++i)
            w[i] = *(const float2*)(Whh0 + (size_t)(i * 32 + ks) * 1024 + c0 + cp * 2);
        const int rb = tid & 7, rc = tid >> 3;   // reducers (tid<128): rc 0..15

        for (int t = 0; t < 512; ++t) {
            // prefetch X0 contribution (off the post-reduce critical path)
            float xv = 0.f;
            if (tid < 128) xv = X0[(size_t)(t * 8 + rb) * 1024 + c0 + rc];
            if (t > 0 && wv == 0) {
                int v = __hip_atomic_load(&cnt0[t - 1], __ATOMIC_RELAXED, __HIP_MEMORY_SCOPE_AGENT);
                while (v < 64) {
                    __builtin_amdgcn_s_sleep(1);
                    v = __hip_atomic_load(&cnt0[t - 1], __ATOMIC_RELAXED, __HIP_MEMORY_SCOPE_AGENT);
                }
            }
            asm volatile("" ::: "memory");
            __syncthreads();
            {   // stage h0_{t-1} (row t): normal cached global->LDS
                const float* src = H0 + (size_t)t * 8192;
#pragma unroll
                for (int q = 0; q < 8; ++q) {
                    const int ch = wv * 8 + q;
                    gl_lds16(hl0 + ch * 256, src + ch * 256 + lid * 4);
                }
            }
            __syncthreads();
            float y0[8], y1[8];
#pragma unroll
            for (int b = 0; b < 8; ++b) { y0[b] = 0.f; y1[b] = 0.f; }
#pragma unroll
            for (int i = 0; i < 32; ++i) {
                const int k = i * 32 + ks;
                const float4 ha = *(const float4*)(hl0 + (k << 3));
                const float4 hb = *(const float4*)(hl0 + (k << 3) + 4);
                const float wa = w[i].x, wb = w[i].y;
                y0[0] += ha.x * wa; y0[1] += ha.y * wa; y0[2] += ha.z * wa; y0[3] += ha.w * wa;
                y0[4] += hb.x * wa; y0[5] += hb.y * wa; y0[6] += hb.z * wa; y0[7] += hb.w * wa;
                y1[0] += ha.x * wb; y1[1] += ha.y * wb; y1[2] += ha.z * wb; y1[3] += ha.w * wb;
                y1[4] += hb.x * wb; y1[5] += hb.y * wb; y1[6] += hb.z * wb; y1[7] += hb.w * wb;
            }
#pragma unroll
            for (int b = 0; b < 8; ++b) {
                part[ks * 136 + (cp * 2 + 0) * 8 + b] = y0[b];
                part[ks * 136 + (cp * 2 + 1) * 8 + b] = y1[b];
            }
            __syncthreads();
            if (tid < 128) {
                float s = 0.f;
                for (int kr = 0; kr < 32; ++kr) s += part[kr * 136 + rc * 8 + rb];
                s += xv;
                const float hv = tanhf(s);
                // coherent write-through store (sc0 sc1): no wbl2 needed later
                __hip_atomic_store(&H0[(size_t)(t + 1) * 8192 + (c0 + rc) * 8 + rb], hv,
                                   __ATOMIC_RELAXED, __HIP_MEMORY_SCOPE_AGENT);
                if (t == 511) oh0[rb * 1024 + c0 + rc] = hv;
            }
            __syncthreads();   // drains vmcnt(0): stores are at coherence point
            if (tid == 0)
                __hip_atomic_fetch_add(&cnt0[t], 1, __ATOMIC_RELAXED, __HIP_MEMORY_SCOPE_AGENT);
        }
    } else if (bid < 192) {
        // ================= layer 1 =================
        const int j = bid - 64, c0 = j * 8;
        const int ks = tid >> 2, cp = tid & 3;   // ks 0..63 (16 k's each), 4 col-pairs
        float2 wi[16], wh[16];
#pragma unroll
        for (int i = 0; i < 16; ++i) {
            wi[i] = *(const float2*)(Wih1 + (size_t)(i * 64 + ks) * 1024 + c0 + cp * 2);
            wh[i] = *(const float2*)(Whh1 + (size_t)(i * 64 + ks) * 1024 + c0 + cp * 2);
        }
        const int rb = tid & 7, rc = tid >> 3;   // reducers (tid<64): rc 0..7
        float biasc = 0.f;
        if (tid < 64) biasc = bih1[c0 + rc] + bhh1[c0 + rc];

        for (int t = 0; t < 512; ++t) {
            if (wv == 0) {
                int v = __hip_atomic_load(&cnt0[t], __ATOMIC_RELAXED, __HIP_MEMORY_SCOPE_AGENT);
                while (v < 64) {
                    __builtin_amdgcn_s_sleep(1);
                    v = __hip_atomic_load(&cnt0[t], __ATOMIC_RELAXED, __HIP_MEMORY_SCOPE_AGENT);
                }
            } else if (t > 0 && wv == 1) {
                int v = __hip_atomic_load(&cnt1[t - 1], __ATOMIC_RELAXED, __HIP_MEMORY_SCOPE_AGENT);
                while (v < 128) {
                    __builtin_amdgcn_s_sleep(1);
                    v = __hip_atomic_load(&cnt1[t - 1], __ATOMIC_RELAXED, __HIP_MEMORY_SCOPE_AGENT);
                }
            }
            asm volatile("" ::: "memory");
            __syncthreads();
            {   // stage h0_t (row t+1) AND h1_{t-1} (row t) in one phase
                const float* s0 = H0 + (size_t)(t + 1) * 8192;
                const float* s1 = H1 + (size_t)t * 8192;
#pragma unroll
                for (int q = 0; q < 8; ++q) {
                    const int ch = wv * 8 + q;
                    gl_lds16(hl0 + ch * 256, s0 + ch * 256 + lid * 4);
                    gl_lds16(hl1 + ch * 256, s1 + ch * 256 + lid * 4);
                }
            }
            __syncthreads();
            float y0[8], y1[8];
#pragma unroll
            for (int b = 0; b < 8; ++b) { y0[b] = 0.f; y1[b] = 0.f; }
#pragma unroll
            for (int i = 0; i < 16; ++i) {
                const int k = i * 64 + ks;
                const float4 ha = *(const float4*)(hl0 + (k << 3));
                const float4 hb = *(const float4*)(hl0 + (k << 3) + 4);
                const float4 ga = *(const float4*)(hl1 + (k << 3));
                const float4 gb = *(const float4*)(hl1 + (k << 3) + 4);
                {   const float wa = wi[i].x, wb = wi[i].y;
                    y0[0] += ha.x * wa; y0[1] += ha.y * wa; y0[2] += ha.z * wa; y0[3] += ha.w * wa;
                    y0[4] += hb.x * wa; y0[5] += hb.y * wa; y0[6] += hb.z * wa; y0[7] += hb.w * wa;
                    y1[0] += ha.x * wb; y1[1] += ha.y * wb; y1[2] += ha.z * wb; y1[3] += ha.w * wb;
                    y1[4] += hb.x * wb; y1[5] += hb.y * wb; y1[6] += hb.z * wb; y1[7] += hb.w * wb; }
                {   const float wa = wh[i].x, wb = wh[i].y;
                    y0[0] += ga.x * wa; y0[1] += ga.y * wa; y0[2] += ga.z * wa; y0[3] += ga.w * wa;
                    y0[4] += gb.x * wa; y0[5] += gb.y * wa; y0[6] += gb.z * wa; y0[7] += gb.w * wa;
                    y1[0] += ga.x * wb; y1[1] += ga.y * wb; y1[2] += ga.z * wb; y1[3] += ga.w * wb;
                    y1[4] += gb.x * wb; y1[5] += gb.y * wb; y1[6] += gb.z * wb; y1[7] += gb.w * wb; }
            }
#pragma unroll
            for (int b = 0; b < 8; ++b) {
                part[ks * 65 + (cp * 2 + 0) * 8 + b] = y0[b];
                part[ks * 65 + (cp * 2 + 1) * 8 + b] = y1[b];
            }
            __syncthreads();
            if (tid < 64) {
                float s = biasc;
                for (int kr = 0; kr < 64; ++kr) s += part[kr * 65 + rc * 8 + rb];
                const float hv = tanhf(s);
                __hip_atomic_store(&H1[(size_t)(t + 1) * 8192 + (c0 + rc) * 8 + rb], hv,
                                   __ATOMIC_RELAXED, __HIP_MEMORY_SCOPE_AGENT);
                H1b[(size_t)(rb * 512 + t) * 1024 + c0 + rc] = f2bf(hv);  // read next dispatch
                if (t == 511) oh1[rb * 1024 + c0 + rc] = hv;
            }
            __syncthreads();   // drains vmcnt(0): stores are at coherence point
            if (tid == 0)
                __hip_atomic_fetch_add(&cnt1[t], 1, __ATOMIC_RELAXED, __HIP_MEMORY_SCOPE_AGENT);
        }
    } else {
        // ============ blocks 192..255: W_out transpose (hidden) ============
        unsigned short* lt = (unsigned short*)smem;   // 128*136*2 = 34816 B <= 82944
        for (int tile = bid - 192; tile < 2000; tile += 64) {
            const int kt = tile / 250, ntw = tile % 250;
            const int krow = tid >> 5, ncol = (tid & 31) * 4;
            for (int it = 0; it < 16; ++it) {
                const int kl = it * 8 + krow;
                const float4 v = *(const float4*)(Wout + (size_t)(kt * 128 + kl) * 32000 + ntw * 128 + ncol);
                lt[(ncol + 0) * 136 + kl] = f2bf(v.x);
                lt[(ncol + 1) * 136 + kl] = f2bf(v.y);
                lt[(ncol + 2) * 136 + kl] = f2bf(v.z);
                lt[(ncol + 3) * 136 + kl] = f2bf(v.w);
            }
            __syncthreads();
            const int sg = tid & 15;
            for (int ot = 0; ot < 8; ++ot) {
                const int nl = ot * 16 + (tid >> 4);
                const uint4 u = *(uint4*)&lt[nl * 136 + sg * 8];
                *(uint4*)(WT + (size_t)(ntw * 128 + nl) * 1024 + kt * 128 + sg * 8) = u;
            }
            __syncthreads();   // lt reused next tile
        }
    }
}

// ---------------------------------------------------------------------------
// K3: logits[m=b*512+t][n] = H1b[m][:] @ W_out[:, n] + b_out[n]
// Round-9: 512-thread blocks, 256x128 output tile, 8 waves (4m x 2n), BK=64,
// 16x16x32 bf16 MFMA. Same proven fragment math/epilogue as the 128^2 m97
// structure; B panel staged once per 256 output rows (was once per 128) ->
// B traffic and per-wave staging rows reduced. No inter-block sync.
// A = H1b [4096][1024] bf16, B = WT [32000][1024] bf16 (= W_out^T).
// ---------------------------------------------------------------------------
__global__ __launch_bounds__(512) void k_logits(const unsigned short* __restrict__ A,
                                                const unsigned short* __restrict__ Bt,
                                                const float* __restrict__ bout,
                                                float* __restrict__ C) {
    __shared__ unsigned short Al[256 * 64];   // 32 KB
    __shared__ unsigned short Bl[128 * 64];   // 16 KB
    const int tid = threadIdx.x;
    const int nt = blockIdx.x % 250, mt2 = blockIdx.x / 250;   // mt2 0..15
    const size_t m0 = (size_t)mt2 * 256, n0 = (size_t)nt * 128;
    const int wv = tid >> 6, lane = tid & 63;
    const int wm = wv >> 1, wn = wv & 1;      // 4m x 2n wave grid
    const int row8 = lane >> 3, sg = lane & 7;
    const int lr = lane & 15, qd = lane >> 4;

    f32x4 acc[4][4];
#pragma unroll
    for (int mi = 0; mi < 4; ++mi)
#pragma unroll
        for (int ni = 0; ni < 4; ++ni) acc[mi][ni] = (f32x4)(0.f);

    for (int kb = 0; kb < 16; ++kb) {
#pragma unroll
        for (int q = 0; q < 4; ++q) {   // A: 8 waves x 4 x 8 rows = 256
            const int rbase = wv * 32 + q * 8;
            gl_lds16(Al + rbase * 64, A + (m0 + rbase + row8) * 1024 + kb * 64 + sg * 8);
        }
#pragma unroll
        for (int q = 0; q < 2; ++q) {   // B: 8 waves x 2 x 8 rows = 128
            const int rbase = wv * 16 + q * 8;
            gl_lds16(Bl + rbase * 64, Bt + (n0 + rbase + row8) * 1024 + kb * 64 + sg * 8);
        }
        __syncthreads();
#pragma unroll
        for (int kk = 0; kk < 2; ++kk) {
            s16x8 af[4], bfr[4];
#pragma unroll
            for (int mi = 0; mi < 4; ++mi)
                af[mi] = *(const s16x8*)&Al[(wm * 64 + mi * 16 + lr) * 64 + kk * 32 + qd * 8];
#pragma unroll
            for (int ni = 0; ni < 4; ++ni)
                bfr[ni] = *(const s16x8*)&Bl[(wn * 64 + ni * 16 + lr) * 64 + kk * 32 + qd * 8];
#pragma unroll
            for (int mi = 0; mi < 4; ++mi)
#pragma unroll
                for (int ni = 0; ni < 4; ++ni)
                    acc[mi][ni] = __builtin_amdgcn_mfma_f32_16x16x32_bf16(af[mi], bfr[ni], acc[mi][ni], 0, 0, 0);
        }
        __syncthreads();
    }
#pragma unroll
    for (int ni = 0; ni < 4; ++ni) {
        const size_t n = n0 + wn * 64 + ni * 16 + lr;
        const float bo = bout[n];
#pragma unroll
        for (int mi = 0; mi < 4; ++mi) {
#pragma unroll
            for (int r = 0; r < 4; ++r) {
                const size_t m = m0 + wm * 64 + mi * 16 + qd * 4 + r;
                C[m * 32000 + n] = acc[mi][ni][r] + bo;
            }
        }
    }
}

// ---------------------------------------------------------------------------
extern "C" void kernel_launch(void* const* d_in, const int* in_sizes, int n_in,
                              void* d_out, int out_size, void* d_ws, size_t ws_size,
                              hipStream_t stream) {
    const int* x      = (const int*)d_in[0];
    const float* emb  = (const float*)d_in[1];
    const float* Wih0 = (const float*)d_in[2];
    const float* bih0 = (const float*)d_in[3];
    const float* Whh0 = (const float*)d_in[4];
    const float* bhh0 = (const float*)d_in[5];
    const float* Wih1 = (const float*)d_in[6];
    const float* bih1 = (const float*)d_in[7];
    const float* Whh1 = (const float*)d_in[8];
    const float* bhh1 = (const float*)d_in[9];
    const float* Wout = (const float*)d_in[10];
    const float* bout = (const float*)d_in[11];

    char* ws = (char*)d_ws;
    float* X0           = (float*)(ws + 0);          // 16,777,216 B
    float* H0           = (float*)(ws + 16777216);   // 513*8192*4 = 16,809,984 B
    float* H1           = (float*)(ws + 33587200);   // 16,809,984 B
    unsigned short* H1b = (unsigned short*)(ws + 50397184);  // 8,388,608 B
    unsigned short* WT  = (unsigned short*)(ws + 58785792);  // 65,536,000 B
    int* cnt0           = (int*)(ws + 124321792);    // 512*4 = 2048 B
    int* cnt1           = cnt0 + 512;                // 512*4 = 2048 B

    float* out = (float*)d_out;
    float* oh0 = out + 131072000ll;   // 4096*32000
    float* oh1 = oh0 + 8192;

    // ws is re-poisoned before every launch: re-zero initial states + counters
    hipMemsetAsync(H0, 0, 32768, stream);
    hipMemsetAsync(H1, 0, 32768, stream);
    hipMemsetAsync(cnt0, 0, 4096, stream);

    k_x0<<<256, 256, 0, stream>>>(x, emb, Wih0, bih0, bhh0, X0);
    k_scan<<<256, 256, 0, stream>>>(X0, H0, H1, H1b, Whh0, Wih1, Whh1,
                                    bih1, bhh1, cnt0, cnt1, oh0, oh1, Wout, WT);
    k_logits<<<4000, 512, 0, stream>>>(H1b, WT, bout, out);
}